// Round 11
// baseline (185.920 us; speedup 1.0000x reference)
//
#include <hip/hip_runtime.h>
#include <hip/hip_fp16.h>

// NCC loss, v17: v16 + FULL named-register ring -> 3 blocks/CU.
// v16 facts: DMA staging correct (absmax 0), hybrid ring with 4 named-reg
// slots cost only VGPR=60 (vs v12's array-ring 112) -> named slots ~2 VGPR
// each. Occupancy has been LDS-capped at 2 blocks/CU (37%) since v10; every
// in-budget pipelining attempt failed to move the stall.
// v17: all 9 ring slots in named regs (if-else on literal jj, v16 pattern).
// LDS 73.7 -> 48.1KB -> 3 blocks/CU (24 waves, +50%). FCH 40->20 (960
// blocks) so the grid can fill 3/CU; D-halo 1.2->1.4x (+17% work) is the
// price, paid for by +50% latency-hiding. Rest = v16 verbatim.
// Key check: VGPR must be <=85 (6 waves/SIMD). >85 falsifies -> revert FCH.
#define ND 2
#define DD 160
#define HH 192
#define WW 160
#define HW (HH * WW)
#define DHW (DD * HH * WW)

constexpr int TW  = 32;            // tile width  (outputs)
constexpr int TH  = 16;            // tile height (outputs) -> 512 columns
constexpr int HLO = TH + 8;        // 24 rows incl. H halo
constexpr int FCH = 20;            // d outputs per block
constexpr int NCH = DD / FCH;      // 8 chunks
constexpr int NSL = FCH + 8;       // 28 slices streamed
constexpr int NR  = NSL / 2;       // 14 rounds, 2 slices each

struct alignas(8) h4 { __half2 lo, hi; };

__device__ __forceinline__ void slide4(const float x[12], float S[4]) {
    float f = ((x[0] + x[1]) + (x[2] + x[3]))
            + ((x[4] + x[5]) + (x[6] + x[7])) + x[8];
    S[0] = f;
    f += x[9]  - x[0]; S[1] = f;
    f += x[10] - x[1]; S[2] = f;
    f += x[11] - x[2]; S[3] = f;
}

__global__ __launch_bounds__(512)
void ncc_fused7(const float* __restrict__ I, const float* __restrict__ J,
                float* __restrict__ outp)
{
    // raw input staging: per slice-slot an 8KB region:
    //   floats [0,960)    : I rows, 24 x 40 (row r at r*40)
    //   floats [960,1920) : J rows
    //   floats [1920,2048): pad (DMA overrun slots)
    __shared__ float  sraw[2][2048];                // 16,384 B
    // stage-A output: centered W-sums (f32, v10 format), 2 slices
    __shared__ float4 sws[2][HLO][TW + 1];          // 25,344 B
    __shared__ float  sw4[2][HLO][TW + 1];          //  6,336 B
    __shared__ float  wred[8];                      // total 48,096 B

    const int tid = threadIdx.x;
    const int w0  = blockIdx.x * TW;                // 0..128
    const int h0  = blockIdx.y * TH;                // 0..176
    const int z   = blockIdx.z;                     // 0..15
    const int n   = z >> 3;
    const int d0  = (z & 7) * FCH;

    // ---- stage-A role: 384 jobs = 2 slices x 24 rows x 8 groups ----
    const bool ajob = (tid < 384);
    const int  sl   = tid / 192;                    // slice-of-round (0/1)
    const int  rj   = tid - sl * 192;
    const int  arow = rj >> 3;                      // 0..23
    const int  awg  = rj & 7;                       // 0..7
    const int  agh  = h0 + arow - 4;
    const bool ahok = (agh >= 0) && (agh < HH);
    const int  agws = w0 + awg * 4 - 4;

    // ---- stage-B role: one (h,w) column per thread (all 512) ----
    const int oh = tid >> 5;                        // 0..15
    const int ow = tid & 31;                        // 0..31
    const int h  = h0 + oh, w = w0 + ow;
    const float cW  = (float)(min(w + 4, WW - 1) - max(w - 4, 0) + 1);
    const float cH  = (float)(min(h + 4, HH - 1) - max(h - 4, 0) + 1);
    const float cHW = cW * cH;

    // ---- DMA role: chunk `tid` of each slice region (round-invariant) ----
    const bool chI   = tid < 240;
    const bool chPad = tid >= 480;
    const int  cr    = chI ? tid : (tid - 240);     // 0..239 when real
    const int  crow  = cr / 10, cwc = cr - crow * 10;
    const int  cgh   = h0 + crow - 4;
    const int  cgw   = w0 - 4 + cwc * 4;
    const bool spok  = !chPad && cgh >= 0 && cgh < HH && cgw >= 0 && cgw < WW;
    const float* fptr = chI ? I : J;
    const int  spoff = spok ? (cgh * WW + cgw) : 0;
    // wave-uniform LDS dest base: chunk (tid & ~63), lane adds l*16
    const int  ldsbase = (tid & ~63) * 4;           // float index

    auto stage = [&](int p, int dd) {               // DMA one slice -> sraw[p]
        const bool dok = (dd >= 0) && (dd < DD);
        const float* src = (dok && spok)
            ? (fptr + (size_t)(n * DD + dd) * HW + spoff)
            : fptr;                                  // clamped-safe address
        __builtin_amdgcn_global_load_lds(
            (const __attribute__((address_space(1))) void*)src,
            (__attribute__((address_space(3))) void*)&sraw[p][ldsbase],
            16, 0, 0);
    };

    // D-ring: all 9 slots in NAMED registers (v16-proven ~2 VGPR/slot)
    h4 rg0, rg1, rg2, rg3, rg4, rg5, rg6, rg7, rg8;
    __half rs0, rs1, rs2, rs3, rs4, rs5, rs6, rs7, rs8;
    {
        h4 zz; zz.lo = __floats2half2_rn(0.f, 0.f); zz.hi = zz.lo;
        const __half z1 = __float2half(0.f);
        rg0 = rg1 = rg2 = rg3 = rg4 = rg5 = rg6 = rg7 = rg8 = zz;
        rs0 = rs1 = rs2 = rs3 = rs4 = rs5 = rs6 = rs7 = rs8 = z1;
    }

    float run0 = 0.f, run1 = 0.f, run2 = 0.f, run3 = 0.f, run4 = 0.f;
    float acc = 0.f;
    const float inv = 1.0f / 729.0f;

    // prologue: stage slices 0,1 of this chunk
    stage(0, d0 - 4 + 0);
    stage(1, d0 - 4 + 1);
    __syncthreads();                                 // drains DMA (vmcnt 0)

    #pragma unroll 1
    for (int g = 0; g < 2; ++g) {                    // 2 x 9 = 18 >= NR
        #pragma unroll
        for (int r = 0; r < 9; ++r) {
            const int rr = g * 9 + r;
            if (rr < NR) {
                const int s0  = 2 * rr;
                const int dd0 = d0 - 4 + s0;
                // ---- stage A: slides from LDS-resident raw rows ----
                if (ajob) {
                    const int dd = dd0 + sl;
                    const bool dok = (dd >= 0) && (dd < DD);
                    float a[12], b[12];
                    const int fi = arow * 40 + awg * 4;
                    #pragma unroll
                    for (int c = 0; c < 3; ++c) {
                        const int gw = agws + 4 * c;
                        float4 va = *(const float4*)&sraw[sl][fi + 4 * c];
                        float4 vb = *(const float4*)&sraw[sl][960 + fi + 4 * c];
                        if (dok && ahok && gw >= 0 && gw < WW) {
                            va.x -= 0.5f; va.y -= 0.5f; va.z -= 0.5f; va.w -= 0.5f;
                            vb.x -= 0.5f; vb.y -= 0.5f; vb.z -= 0.5f; vb.w -= 0.5f;
                        } else {
                            va = make_float4(0.f, 0.f, 0.f, 0.f); vb = va;
                        }
                        *(float4*)&a[4 * c] = va;
                        *(float4*)&b[4 * c] = vb;
                    }
                    if (dok) {
                        float S0[4], S1[4], S2[4], S3[4], S4[4], f[12];
                        slide4(a, S0);
                        slide4(b, S1);
                        #pragma unroll
                        for (int i = 0; i < 12; ++i) f[i] = a[i] * a[i];
                        slide4(f, S2);
                        #pragma unroll
                        for (int i = 0; i < 12; ++i) f[i] = b[i] * b[i];
                        slide4(f, S3);
                        #pragma unroll
                        for (int i = 0; i < 12; ++i) f[i] = a[i] * b[i];
                        slide4(f, S4);
                        #pragma unroll
                        for (int t = 0; t < 4; ++t) {
                            sws[sl][arow][awg * 4 + t] =
                                make_float4(S0[t], S1[t], S2[t], S3[t]);
                            sw4[sl][arow][awg * 4 + t] = S4[t];
                        }
                    }
                }
                __syncthreads();                     // bar1: sws ready, sraw free
                // ---- DMA next round's slices (lands by bar2) ----
                if (rr + 1 < NR) {
                    stage(0, dd0 + 2);
                    stage(1, dd0 + 3);
                }
                // ---- stage B: taps + named-reg ring + cc ----
                #pragma unroll
                for (int half = 0; half < 2; ++half) {
                    const int s   = s0 + half;
                    const int ddx = dd0 + half;
                    float t0 = 0.f, t1 = 0.f, t2 = 0.f, t3 = 0.f, t4 = 0.f;
                    if (ddx >= 0 && ddx < DD) {
                        #pragma unroll
                        for (int q = 0; q < 9; ++q) {
                            const float4 v = sws[half][oh + q][ow];
                            t0 += v.x; t1 += v.y; t2 += v.z; t3 += v.w;
                            t4 += sw4[half][oh + q][ow];
                        }
                    }
                    h4 nh;
                    nh.lo = __floats2half2_rn(t0, t1);
                    nh.hi = __floats2half2_rn(t2, t3);
                    const __half n4h = __float2half(t4);
                    const int jj = (2 * r + half) % 9;   // literal after unroll
                    h4 po; __half p4;
                    if      (jj == 0) { po = rg0; p4 = rs0; }
                    else if (jj == 1) { po = rg1; p4 = rs1; }
                    else if (jj == 2) { po = rg2; p4 = rs2; }
                    else if (jj == 3) { po = rg3; p4 = rs3; }
                    else if (jj == 4) { po = rg4; p4 = rs4; }
                    else if (jj == 5) { po = rg5; p4 = rs5; }
                    else if (jj == 6) { po = rg6; p4 = rs6; }
                    else if (jj == 7) { po = rg7; p4 = rs7; }
                    else              { po = rg8; p4 = rs8; }
                    run0 += __low2float(nh.lo)  - __low2float(po.lo);
                    run1 += __high2float(nh.lo) - __high2float(po.lo);
                    run2 += __low2float(nh.hi)  - __low2float(po.hi);
                    run3 += __high2float(nh.hi) - __high2float(po.hi);
                    run4 += __half2float(n4h)   - __half2float(p4);
                    if      (jj == 0) { rg0 = nh; rs0 = n4h; }
                    else if (jj == 1) { rg1 = nh; rs1 = n4h; }
                    else if (jj == 2) { rg2 = nh; rs2 = n4h; }
                    else if (jj == 3) { rg3 = nh; rs3 = n4h; }
                    else if (jj == 4) { rg4 = nh; rs4 = n4h; }
                    else if (jj == 5) { rg5 = nh; rs5 = n4h; }
                    else if (jj == 6) { rg6 = nh; rs6 = n4h; }
                    else if (jj == 7) { rg7 = nh; rs7 = n4h; }
                    else              { rg8 = nh; rs8 = n4h; }
                    if (s >= 8) {
                        const int d = d0 + s - 8;
                        const float cD  = (float)(min(d + 4, DD - 1) - max(d - 4, 0) + 1);
                        const float cnt = cHW * cD;
                        // reconstruct uncentered box sums (exact algebra)
                        const float Is = run0 + 0.5f * cnt;
                        const float Js = run1 + 0.5f * cnt;
                        const float I2 = run2 + run0 + 0.25f * cnt;
                        const float J2 = run3 + run1 + 0.25f * cnt;
                        const float IJ = run4 + 0.5f * (run0 + run1) + 0.25f * cnt;
                        const float uI = Is * inv, uJ = Js * inv;
                        const float cross = IJ - uI * Js;
                        const float Iv = fmaxf(I2 - uI * Is, 1e-5f);
                        const float Jv = fmaxf(J2 - uJ * Js, 1e-5f);
                        acc += cross * cross / (Iv * Jv + 1e-5f);
                    }
                }
                __syncthreads();                     // bar2: drains DMA vmcnt
            }
        }
    }

    // ---- block reduction, one fp32 atomic per block ----
    #pragma unroll
    for (int off = 32; off > 0; off >>= 1)
        acc += __shfl_down(acc, off, 64);
    const int lane = tid & 63, wid = tid >> 6;
    if (lane == 0) wred[wid] = acc;
    __syncthreads();
    if (tid == 0) {
        float ssum = 0.f;
        #pragma unroll
        for (int i = 0; i < 8; ++i) ssum += wred[i];
        atomicAdd(outp, -ssum);
    }
}

extern "C" void kernel_launch(void* const* d_in, const int* in_sizes, int n_in,
                              void* d_out, int out_size, void* d_ws, size_t ws_size,
                              hipStream_t stream)
{
    const float* I = (const float*)d_in[0];   // y_true
    const float* J = (const float*)d_in[1];   // y_pred
    float* out = (float*)d_out;

    hipMemsetAsync(out, 0, sizeof(float), stream);
    dim3 grid(WW / TW, HH / TH, ND * NCH);    // 5 x 12 x 16 = 960 blocks
    ncc_fused7<<<grid, 512, 0, stream>>>(I, J, out);
}

// Round 12
// 163.283 us; speedup vs baseline: 1.1386x; 1.1386x over previous
//
#include <hip/hip_runtime.h>
#include <hip/hip_fp16.h>

// NCC loss, v18: 32x32 tile, h-pair stage B, 14 double-rounds, DMA staging.
// v17 decode: occupancy fell because 960 blocks > 768 resident slots ->
// ragged 2-phase run (every 960-block cfg reads ~20%, every 480-block ~37%).
// When grid <= capacity, ALL blocks co-resident and kernel time = block time.
// So: cut block time. v18 vs v16 per output: stage-B taps 9 -> 5 (v7-proven
// h-pair: 10 taps/2 outputs), stage-B VALU -26%, barriers/output halved
// (14 rounds x 2 slices x 1024 outputs vs 24 x 2 x 512). All 512 threads
// tap (v13 lesson). Ring = 2 named-reg sets (v16/v17 proven ~2 VGPR/slot).
// FCH=20 -> grid 480 <= 512 slots, co-resident. LDS 79.5KB -> 2 blocks/CU.
// Round skeleton + DMA pattern = v16 verbatim. Key checks: VGPR<=128, WRITE~0.
#define ND 2
#define DD 160
#define HH 192
#define WW 160
#define HW (HH * WW)
#define DHW (DD * HH * WW)

constexpr int TW  = 32;            // tile width  (outputs)
constexpr int TH  = 32;            // tile height (outputs) -> 1024 columns
constexpr int HLO = TH + 8;        // 40 rows incl. H halo
constexpr int FCH = 20;            // d outputs per block
constexpr int NCH = DD / FCH;      // 8 chunks
constexpr int NSL = FCH + 8;       // 28 slices streamed
constexpr int NR  = NSL / 2;       // 14 rounds, 2 slices each

struct alignas(8) h4 { __half2 lo, hi; };

__device__ __forceinline__ void slide4(const float x[12], float S[4]) {
    float f = ((x[0] + x[1]) + (x[2] + x[3]))
            + ((x[4] + x[5]) + (x[6] + x[7])) + x[8];
    S[0] = f;
    f += x[9]  - x[0]; S[1] = f;
    f += x[10] - x[1]; S[2] = f;
    f += x[11] - x[2]; S[3] = f;
}

// ring+run update for one output column's slot
#define RUPD(RG, RS, NH, N4, P0, P1, P2, P3, P4)            \
    P0 += __low2float((NH).lo)  - __low2float((RG).lo);     \
    P1 += __high2float((NH).lo) - __high2float((RG).lo);    \
    P2 += __low2float((NH).hi)  - __low2float((RG).hi);     \
    P3 += __high2float((NH).hi) - __high2float((RG).hi);    \
    P4 += __half2float(N4)      - __half2float(RS);         \
    RG = (NH); RS = (N4);

__global__ __launch_bounds__(512)
void ncc_fused8(const float* __restrict__ I, const float* __restrict__ J,
                float* __restrict__ outp)
{
    // raw input staging per slice-slot: I rows [0,1600), J rows [1600,3200),
    // pad [3200,3328) (DMA masked-lane overrun safety). Row r at r*40.
    __shared__ float  sraw[2][3328];                // 26,624 B
    // stage-A output: centered W-sums (f32), 2 slices, 40 rows x 32 cols
    __shared__ float4 sws[2][HLO][TW + 1];          // 42,240 B
    __shared__ float  sw4[2][HLO][TW + 1];          // 10,560 B
    __shared__ float  wred[8];                      // total 79,456 B

    const int tid = threadIdx.x;
    const int w0  = blockIdx.x * TW;                // 0..128
    const int h0  = blockIdx.y * TH;                // 0..160
    const int z   = blockIdx.z;                     // 0..15
    const int n   = z >> 3;
    const int d0  = (z & 7) * FCH;

    // ---- stage-B role: h-pair (hp, hp+1) x ow per thread ----
    const int hp = (tid >> 5) * 2;                  // 0,2,..,30
    const int ow = tid & 31;                        // 0..31
    const int ha = h0 + hp, hb = ha + 1, wg = w0 + ow;
    const float cWv  = (float)(min(wg + 4, WW - 1) - max(wg - 4, 0) + 1);
    const float cHWa = cWv * (float)(min(ha + 4, HH - 1) - max(ha - 4, 0) + 1);
    const float cHWb = cWv * (float)(min(hb + 4, HH - 1) - max(hb - 4, 0) + 1);

    // ---- DMA role: chunk tid and (tid<288) chunk 512+tid of 800 per slice ----
    // chunk c: field = c<400 ? I : J; cr = c%400; row = cr/10; wc = cr%10
    const bool c1I  = tid < 400;
    const int  cr1  = c1I ? tid : tid - 400;
    const int  cro1 = cr1 / 10, cwc1 = cr1 - cro1 * 10;
    const int  gh1  = h0 + cro1 - 4, gw1 = w0 - 4 + cwc1 * 4;
    const bool sp1  = gh1 >= 0 && gh1 < HH && gw1 >= 0 && gw1 < WW;
    const float* f1 = c1I ? I : J;
    const int  o1   = sp1 ? (gh1 * WW + gw1) : 0;
    const int  cr2  = 112 + tid;                    // chunk2 = 512+tid (J field)
    const int  cro2 = cr2 / 10, cwc2 = cr2 - cro2 * 10;
    const int  gh2  = h0 + cro2 - 4, gw2 = w0 - 4 + cwc2 * 4;
    const bool sp2  = gh2 >= 0 && gh2 < HH && gw2 >= 0 && gw2 < WW;
    const int  o2   = sp2 ? (gh2 * WW + gw2) : 0;
    const int  base1 = (tid & ~63) * 4;             // wave-uniform float index
    const int  base2 = (512 + (tid & ~63)) * 4;

    auto stage = [&](int p, int dd) {               // DMA one slice -> sraw[p]
        const bool dok = (dd >= 0) && (dd < DD);
        const size_t sb = (size_t)(n * DD + dd) * HW;
        const float* s1 = (dok && sp1) ? (f1 + sb + o1) : f1;
        __builtin_amdgcn_global_load_lds(
            (const __attribute__((address_space(1))) void*)s1,
            (__attribute__((address_space(3))) void*)&sraw[p][base1], 16, 0, 0);
        if (tid < 288) {
            const float* s2 = (dok && sp2) ? (J + sb + o2) : J;
            __builtin_amdgcn_global_load_lds(
                (const __attribute__((address_space(1))) void*)s2,
                (__attribute__((address_space(3))) void*)&sraw[p][base2], 16, 0, 0);
        }
    };

    // D-ring: 9 slots x 2 output columns, all NAMED registers
    h4 gA0, gA1, gA2, gA3, gA4, gA5, gA6, gA7, gA8;
    h4 gB0, gB1, gB2, gB3, gB4, gB5, gB6, gB7, gB8;
    __half sA0, sA1, sA2, sA3, sA4, sA5, sA6, sA7, sA8;
    __half sB0, sB1, sB2, sB3, sB4, sB5, sB6, sB7, sB8;
    {
        h4 zz; zz.lo = __floats2half2_rn(0.f, 0.f); zz.hi = zz.lo;
        const __half z1 = __float2half(0.f);
        gA0=gA1=gA2=gA3=gA4=gA5=gA6=gA7=gA8=zz;
        gB0=gB1=gB2=gB3=gB4=gB5=gB6=gB7=gB8=zz;
        sA0=sA1=sA2=sA3=sA4=sA5=sA6=sA7=sA8=z1;
        sB0=sB1=sB2=sB3=sB4=sB5=sB6=sB7=sB8=z1;
    }
    float rA0=0.f, rA1=0.f, rA2=0.f, rA3=0.f, rA4=0.f;
    float rB0=0.f, rB1=0.f, rB2=0.f, rB3=0.f, rB4=0.f;
    float acc = 0.f;
    const float inv = 1.0f / 729.0f;

    // prologue: stage slices 0,1
    stage(0, d0 - 4 + 0);
    stage(1, d0 - 4 + 1);
    __syncthreads();                                 // drains DMA (vmcnt 0)

    #pragma unroll 1
    for (int g = 0; g < 2; ++g) {                    // 2 x 9 = 18 >= NR
        #pragma unroll
        for (int r = 0; r < 9; ++r) {
            const int rr = g * 9 + r;
            if (rr < NR) {
                const int s0  = 2 * rr;
                const int dd0 = d0 - 4 + s0;
                // ---- stage A: 640 jobs = 2 slices x 40 rows x 8 groups ----
                #pragma unroll
                for (int jb = 0; jb < 2; ++jb) {
                    const int job = tid + jb * 512;
                    if (job < 8 * HLO * 2) {         // jb=1 -> tid<128
                        const int sl   = job >= 320;
                        const int rj   = job - sl * 320;
                        const int arow = rj >> 3;
                        const int awg  = rj & 7;
                        const int agh  = h0 + arow - 4;
                        const bool ahok = (agh >= 0) && (agh < HH);
                        const int agws = w0 + awg * 4 - 4;
                        const int dd   = dd0 + sl;
                        const bool dok = (dd >= 0) && (dd < DD);
                        float a[12], b[12];
                        const int fi = arow * 40 + awg * 4;
                        #pragma unroll
                        for (int c = 0; c < 3; ++c) {
                            const int gw = agws + 4 * c;
                            float4 va = *(const float4*)&sraw[sl][fi + 4 * c];
                            float4 vb = *(const float4*)&sraw[sl][1600 + fi + 4 * c];
                            if (dok && ahok && gw >= 0 && gw < WW) {
                                va.x -= 0.5f; va.y -= 0.5f; va.z -= 0.5f; va.w -= 0.5f;
                                vb.x -= 0.5f; vb.y -= 0.5f; vb.z -= 0.5f; vb.w -= 0.5f;
                            } else {
                                va = make_float4(0.f, 0.f, 0.f, 0.f); vb = va;
                            }
                            *(float4*)&a[4 * c] = va;
                            *(float4*)&b[4 * c] = vb;
                        }
                        if (dok) {
                            float S0[4], S1[4], S2[4], S3[4], S4[4], f[12];
                            slide4(a, S0);
                            slide4(b, S1);
                            #pragma unroll
                            for (int i = 0; i < 12; ++i) f[i] = a[i] * a[i];
                            slide4(f, S2);
                            #pragma unroll
                            for (int i = 0; i < 12; ++i) f[i] = b[i] * b[i];
                            slide4(f, S3);
                            #pragma unroll
                            for (int i = 0; i < 12; ++i) f[i] = a[i] * b[i];
                            slide4(f, S4);
                            #pragma unroll
                            for (int t = 0; t < 4; ++t) {
                                sws[sl][arow][awg * 4 + t] =
                                    make_float4(S0[t], S1[t], S2[t], S3[t]);
                                sw4[sl][arow][awg * 4 + t] = S4[t];
                            }
                        }
                    }
                }
                __syncthreads();                     // bar1: sws ready, sraw free
                // ---- DMA next round's slices (lands by bar2) ----
                if (rr + 1 < NR) {
                    stage(0, dd0 + 2);
                    stage(1, dd0 + 3);
                }
                // ---- stage B: h-pair taps (10 rows / 2 outputs) + ring + cc ----
                #pragma unroll
                for (int half = 0; half < 2; ++half) {
                    const int s   = s0 + half;
                    const int ddx = dd0 + half;
                    float t0=0.f,t1=0.f,t2=0.f,t3=0.f,t4=0.f;
                    float u0=0.f,u1=0.f,u2=0.f,u3=0.f,u4=0.f;
                    if (ddx >= 0 && ddx < DD) {
                        const float4 r0 = sws[half][hp][ow];
                        const float  r04 = sw4[half][hp][ow];
                        t0 = r0.x; t1 = r0.y; t2 = r0.z; t3 = r0.w; t4 = r04;
                        #pragma unroll
                        for (int q = 1; q < 9; ++q) {
                            const float4 v = sws[half][hp + q][ow];
                            t0 += v.x; t1 += v.y; t2 += v.z; t3 += v.w;
                            t4 += sw4[half][hp + q][ow];
                        }
                        const float4 v9 = sws[half][hp + 9][ow];
                        u0 = t0 + v9.x - r0.x;
                        u1 = t1 + v9.y - r0.y;
                        u2 = t2 + v9.z - r0.z;
                        u3 = t3 + v9.w - r0.w;
                        u4 = t4 + sw4[half][hp + 9][ow] - r04;
                    }
                    h4 nhA, nhB;
                    nhA.lo = __floats2half2_rn(t0, t1);
                    nhA.hi = __floats2half2_rn(t2, t3);
                    nhB.lo = __floats2half2_rn(u0, u1);
                    nhB.hi = __floats2half2_rn(u2, u3);
                    const __half n4A = __float2half(t4);
                    const __half n4B = __float2half(u4);
                    const int jj = (2 * r + half) % 9;   // literal after unroll
                    if      (jj == 0) { RUPD(gA0,sA0,nhA,n4A,rA0,rA1,rA2,rA3,rA4)
                                        RUPD(gB0,sB0,nhB,n4B,rB0,rB1,rB2,rB3,rB4) }
                    else if (jj == 1) { RUPD(gA1,sA1,nhA,n4A,rA0,rA1,rA2,rA3,rA4)
                                        RUPD(gB1,sB1,nhB,n4B,rB0,rB1,rB2,rB3,rB4) }
                    else if (jj == 2) { RUPD(gA2,sA2,nhA,n4A,rA0,rA1,rA2,rA3,rA4)
                                        RUPD(gB2,sB2,nhB,n4B,rB0,rB1,rB2,rB3,rB4) }
                    else if (jj == 3) { RUPD(gA3,sA3,nhA,n4A,rA0,rA1,rA2,rA3,rA4)
                                        RUPD(gB3,sB3,nhB,n4B,rB0,rB1,rB2,rB3,rB4) }
                    else if (jj == 4) { RUPD(gA4,sA4,nhA,n4A,rA0,rA1,rA2,rA3,rA4)
                                        RUPD(gB4,sB4,nhB,n4B,rB0,rB1,rB2,rB3,rB4) }
                    else if (jj == 5) { RUPD(gA5,sA5,nhA,n4A,rA0,rA1,rA2,rA3,rA4)
                                        RUPD(gB5,sB5,nhB,n4B,rB0,rB1,rB2,rB3,rB4) }
                    else if (jj == 6) { RUPD(gA6,sA6,nhA,n4A,rA0,rA1,rA2,rA3,rA4)
                                        RUPD(gB6,sB6,nhB,n4B,rB0,rB1,rB2,rB3,rB4) }
                    else if (jj == 7) { RUPD(gA7,sA7,nhA,n4A,rA0,rA1,rA2,rA3,rA4)
                                        RUPD(gB7,sB7,nhB,n4B,rB0,rB1,rB2,rB3,rB4) }
                    else              { RUPD(gA8,sA8,nhA,n4A,rA0,rA1,rA2,rA3,rA4)
                                        RUPD(gB8,sB8,nhB,n4B,rB0,rB1,rB2,rB3,rB4) }
                    if (s >= 8) {
                        const int d = d0 + s - 8;
                        const float cD = (float)(min(d + 4, DD - 1) - max(d - 4, 0) + 1);
                        {   // output A (row hp)
                            const float cnt = cHWa * cD;
                            const float Is = rA0 + 0.5f * cnt;
                            const float Js = rA1 + 0.5f * cnt;
                            const float I2 = rA2 + rA0 + 0.25f * cnt;
                            const float J2 = rA3 + rA1 + 0.25f * cnt;
                            const float IJ = rA4 + 0.5f * (rA0 + rA1) + 0.25f * cnt;
                            const float uI = Is * inv, uJ = Js * inv;
                            const float cross = IJ - uI * Js;
                            const float Iv = fmaxf(I2 - uI * Is, 1e-5f);
                            const float Jv = fmaxf(J2 - uJ * Js, 1e-5f);
                            acc += cross * cross / (Iv * Jv + 1e-5f);
                        }
                        {   // output B (row hp+1)
                            const float cnt = cHWb * cD;
                            const float Is = rB0 + 0.5f * cnt;
                            const float Js = rB1 + 0.5f * cnt;
                            const float I2 = rB2 + rB0 + 0.25f * cnt;
                            const float J2 = rB3 + rB1 + 0.25f * cnt;
                            const float IJ = rB4 + 0.5f * (rB0 + rB1) + 0.25f * cnt;
                            const float uI = Is * inv, uJ = Js * inv;
                            const float cross = IJ - uI * Js;
                            const float Iv = fmaxf(I2 - uI * Is, 1e-5f);
                            const float Jv = fmaxf(J2 - uJ * Js, 1e-5f);
                            acc += cross * cross / (Iv * Jv + 1e-5f);
                        }
                    }
                }
                __syncthreads();                     // bar2: drains DMA vmcnt
            }
        }
    }

    // ---- block reduction, one fp32 atomic per block ----
    #pragma unroll
    for (int off = 32; off > 0; off >>= 1)
        acc += __shfl_down(acc, off, 64);
    const int lane = tid & 63, wid = tid >> 6;
    if (lane == 0) wred[wid] = acc;
    __syncthreads();
    if (tid == 0) {
        float ssum = 0.f;
        #pragma unroll
        for (int i = 0; i < 8; ++i) ssum += wred[i];
        atomicAdd(outp, -ssum);
    }
}

extern "C" void kernel_launch(void* const* d_in, const int* in_sizes, int n_in,
                              void* d_out, int out_size, void* d_ws, size_t ws_size,
                              hipStream_t stream)
{
    const float* I = (const float*)d_in[0];   // y_true
    const float* J = (const float*)d_in[1];   // y_pred
    float* out = (float*)d_out;

    hipMemsetAsync(out, 0, sizeof(float), stream);
    dim3 grid(WW / TW, HH / TH, ND * NCH);    // 5 x 6 x 16 = 480 blocks
    ncc_fused8<<<grid, 512, 0, stream>>>(I, J, out);
}